// Round 22
// baseline (209.196 us; speedup 1.0000x reference)
//
#include <hip/hip_runtime.h>
#include <hip/hip_fp16.h>

#define HID 128
#define EMB 64
#define NG  8192
#define NCLS 16
#define SRCBITS 17    // N=100000 < 2^17; VOCAB=5000 < 2^13
#define SMASK ((1u << SRCBITS) - 1)
#define MMB 64        // nodes per matmul block
#define CAPLOG 6      // 64 slots per node bucket (deg ~ Poisson(10), max ~30)
#define CAP (1 << CAPLOG)

typedef _Float16 f16x8 __attribute__((ext_vector_type(8)));
typedef float    f32x4 __attribute__((ext_vector_type(4)));

// fpext(f16) feeding fmaf -> v_fma_mix_f32
__device__ __forceinline__ void fma8(float* a, uint4 r, float w) {
    const _Float16* h = (const _Float16*)&r;
#pragma unroll
    for (int k = 0; k < 8; ++k) a[k] = fmaf((float)h[k], w, a[k]);
}

// ---------------- zero the padded counter array ----------------
__global__ void k_zero(uint4* __restrict__ p, int n4) {
    int i = blockIdx.x * 256 + threadIdx.x;
    if (i < n4) p[i] = make_uint4(0u, 0u, 0u, 0u);
}

// ---------------- fused degree + bucket fill: ONE edge per thread -------------------
// deg4[4*n] = count for node n (16B stride); bucket[n*CAP + pos] = (vid<<17)|src.
// 1 edge/thread maximizes resident waves -> more atomics in flight machine-wide.
__global__ void k_degfill(const int* __restrict__ src, const int* __restrict__ dst,
                          const int* __restrict__ ids, int E,
                          int* __restrict__ deg4, unsigned* __restrict__ bucket) {
    int e = blockIdx.x * 256 + threadIdx.x;
    if (e < E) {
        int s = src[e], d = dst[e];
        int pos = atomicAdd(&deg4[(size_t)d * 4], 1);
        if (pos < CAP)
            bucket[((size_t)d << CAPLOG) + pos] = ((unsigned)ids[s] << SRCBITS) | (unsigned)s;
    }
}

// ---------------- fused prep: XW=embed@W1 fp16 | wt2=W2^T fp16 | bounds | dinv ------
__global__ void k_prep(const float* __restrict__ embed, const float* __restrict__ W1,
                       const float* __restrict__ W2, const int* __restrict__ batch,
                       const int* __restrict__ deg4,
                       __half* __restrict__ xw, __half* __restrict__ wt2,
                       int* __restrict__ gstart, float* __restrict__ dinv,
                       int V, int N, int xwB, int bndB) {
    int b = (int)blockIdx.x;
    if (b < xwB) {
        int v = (b * 256 + threadIdx.x) >> 6;
        if (v >= V) return;
        int lane = threadIdx.x & 63;
        float ev = embed[(size_t)v * EMB + lane];
        float a0 = 0.f, a1 = 0.f;
#pragma unroll
        for (int k = 0; k < EMB; ++k) {
            float e = __shfl(ev, k, 64);
            float2 w = *(const float2*)&W1[k * HID + 2 * lane];
            a0 = fmaf(e, w.x, a0);
            a1 = fmaf(e, w.y, a1);
        }
        ((__half2*)xw)[(size_t)v * 64 + lane] = __floats2half2_rn(a0, a1);
    } else if (b < xwB + 64) {
        int i = (b - xwB) * 256 + threadIdx.x;   // 64 blocks: 16384
        int c = i >> 7, k = i & 127;
        wt2[i] = __float2half(W2[k * HID + c]);
    } else if (b < xwB + 64 + bndB) {
        int n = (b - xwB - 64) * 256 + threadIdx.x;
        if (n > N) return;
        int bc = (n < N) ? batch[n] : NG;
        int bp = (n > 0) ? batch[n - 1] : -1;
        for (int g = bp + 1; g <= bc; ++g) gstart[g] = n;
    } else {
        int n = (b - xwB - 64 - bndB) * 256 + threadIdx.x;
        if (n < N) dinv[n] = rsqrtf((float)(deg4[(size_t)n * 4] + 1));  // +1 self-loop
    }
}

// ---------------- layer-1 gather: FOUR nodes per wave (16 lanes each) ----------------
// h1[d] = relu( dd*( dd*XW[ids[d]] + sum_e dinv[s_e]*XW[vid_e] ) + b1 )
__global__ void k_gather1(const int* __restrict__ ids, const __half* __restrict__ xw,
                          const unsigned* __restrict__ bucket, const int* __restrict__ deg4,
                          const float* __restrict__ dinv, const float* __restrict__ bias,
                          __half* __restrict__ h1, int N) {
    int wid = (blockIdx.x * blockDim.x + threadIdx.x) >> 6;
    int lane = threadIdx.x & 63;
    int q = lane >> 4;                        // node sub-index 0..3
    int d = wid * 4 + q;
    bool act = d < N;
    int dc = act ? d : N - 1;
    unsigned cb = (unsigned)(lane & 15) << 4; // 16B-chunk byte offset in a 256B row
    int dg = min(deg4[(size_t)dc * 4], CAP);
    int beg = dc << CAPLOG, end = beg + dg;
    float dd = dinv[dc];
    const char* xwb = (const char*)xw;
    float a[8] = {0.f, 0.f, 0.f, 0.f, 0.f, 0.f, 0.f, 0.f};
    {                                          // self term
        uint4 r = *(const uint4*)(xwb + (((unsigned)ids[dc] << 8) | cb));
        fma8(a, r, dd);
    }
    for (int i = beg; i < end; i += 4) {       // 4 edges/node/iter
        float w[4]; unsigned ro[4]; uint4 r[4];
#pragma unroll
        for (int j = 0; j < 4; ++j) {
            int idx = i + j;
            bool v = idx < end;
            unsigned p = bucket[v ? idx : beg];
            w[j] = v ? dinv[p & SMASK] : 0.f;
            ro[j] = v ? (((p >> SRCBITS) << 8) | cb) : cb;
        }
#pragma unroll
        for (int j = 0; j < 4; ++j) r[j] = *(const uint4*)(xwb + ro[j]);
#pragma unroll
        for (int j = 0; j < 4; ++j) fma8(a, r[j], w[j]);
    }
    if (act) {
        int c = lane & 15;
        float4 bl = *(const float4*)&bias[c * 8];
        float4 bh = *(const float4*)&bias[c * 8 + 4];
        __half2 h0 = __floats2half2_rn(fmaxf(fmaf(a[0], dd, bl.x), 0.f),
                                       fmaxf(fmaf(a[1], dd, bl.y), 0.f));
        __half2 h1v = __floats2half2_rn(fmaxf(fmaf(a[2], dd, bl.z), 0.f),
                                        fmaxf(fmaf(a[3], dd, bl.w), 0.f));
        __half2 h2v = __floats2half2_rn(fmaxf(fmaf(a[4], dd, bh.x), 0.f),
                                        fmaxf(fmaf(a[5], dd, bh.y), 0.f));
        __half2 h3 = __floats2half2_rn(fmaxf(fmaf(a[6], dd, bh.z), 0.f),
                                       fmaxf(fmaf(a[7], dd, bh.w), 0.f));
        uint4 pk = make_uint4(*(unsigned*)&h0, *(unsigned*)&h1v,
                              *(unsigned*)&h2v, *(unsigned*)&h3);
        ((uint4*)(h1 + (size_t)dc * HID))[c] = pk;
    }
}

// ---------------- layer-2 matmul via MFMA (swapped operands): h2 = (h1@W2)*dinv -----
__global__ __launch_bounds__(256) void k_mm2_mfma(const __half* __restrict__ h1,
                                                  const __half* __restrict__ wt,
                                                  const float* __restrict__ dinv,
                                                  __half* __restrict__ h2, int N) {
    int tid = threadIdx.x;
    int w = tid >> 6, l = tid & 63;
    int base = blockIdx.x * MMB + w * 16;
    int lrow = l & 15, lkg = l >> 4;
    int node = base + lrow;
    int nc = node < N ? node : N - 1;
    const f16x8* ap = (const f16x8*)(h1 + (size_t)nc * HID);
    f16x8 a0 = ap[0 * 4 + lkg], a1 = ap[1 * 4 + lkg];
    f16x8 a2 = ap[2 * 4 + lkg], a3 = ap[3 * 4 + lkg];
    f32x4 acc[8];
#pragma unroll
    for (int ct = 0; ct < 8; ++ct) acc[ct] = (f32x4){0.f, 0.f, 0.f, 0.f};
    const f16x8* wp = (const f16x8*)wt;   // wt[c][k]: row c = 16 f16x8 chunks
#pragma unroll
    for (int ct = 0; ct < 8; ++ct) {
        const f16x8* bp = wp + (ct * 16 + lrow) * 16 + lkg;
        f16x8 b0 = bp[0], b1 = bp[4], b2 = bp[8], b3 = bp[12];
        acc[ct] = __builtin_amdgcn_mfma_f32_16x16x32_f16(b0, a0, acc[ct], 0, 0, 0);
        acc[ct] = __builtin_amdgcn_mfma_f32_16x16x32_f16(b1, a1, acc[ct], 0, 0, 0);
        acc[ct] = __builtin_amdgcn_mfma_f32_16x16x32_f16(b2, a2, acc[ct], 0, 0, 0);
        acc[ct] = __builtin_amdgcn_mfma_f32_16x16x32_f16(b3, a3, acc[ct], 0, 0, 0);
    }
    if (node < N) {
        float sc = dinv[node];
#pragma unroll
        for (int ct = 0; ct < 8; ++ct) {
            int wc = ct * 16 + lkg * 4;       // 4 consecutive weight-cols
            __half2 lo = __floats2half2_rn(acc[ct][0] * sc, acc[ct][1] * sc);
            __half2 hi = __floats2half2_rn(acc[ct][2] * sc, acc[ct][3] * sc);
            uint2 pk = make_uint2(*(unsigned*)&lo, *(unsigned*)&hi);
            *(uint2*)&h2[(size_t)node * HID + wc] = pk;
        }
    }
}

// ---------------- layer-2 gather: FOUR nodes per wave ----------------
// x2[d] = relu( dd*(h2[d] + sum h2[s]) + b2 )
__global__ void k_gather2(const __half* __restrict__ h2, const unsigned* __restrict__ bucket,
                          const int* __restrict__ deg4, const float* __restrict__ dinv,
                          const float* __restrict__ bias, __half* __restrict__ x2, int N) {
    int wid = (blockIdx.x * blockDim.x + threadIdx.x) >> 6;
    int lane = threadIdx.x & 63;
    int q = lane >> 4;
    int d = wid * 4 + q;
    bool act = d < N;
    int dc = act ? d : N - 1;
    unsigned cb = (unsigned)(lane & 15) << 4;
    int dg = min(deg4[(size_t)dc * 4], CAP);
    int beg = dc << CAPLOG, end = beg + dg;
    float dd = dinv[dc];
    const char* hb = (const char*)h2;
    float a[8] = {0.f, 0.f, 0.f, 0.f, 0.f, 0.f, 0.f, 0.f};
    {                                          // self term (prescaled by dinv already)
        uint4 r = *(const uint4*)(hb + (((unsigned)dc << 8) | cb));
        fma8(a, r, 1.f);
    }
    for (int i = beg; i < end; i += 4) {
        float w[4]; unsigned ro[4]; uint4 r[4];
#pragma unroll
        for (int j = 0; j < 4; ++j) {
            int idx = i + j;
            bool v = idx < end;
            unsigned p = bucket[v ? idx : beg];
            w[j] = v ? 1.f : 0.f;
            ro[j] = v ? (((p & SMASK) << 8) | cb) : cb;
        }
#pragma unroll
        for (int j = 0; j < 4; ++j) r[j] = *(const uint4*)(hb + ro[j]);
#pragma unroll
        for (int j = 0; j < 4; ++j) fma8(a, r[j], w[j]);
    }
    if (act) {
        int c = lane & 15;
        float4 bl = *(const float4*)&bias[c * 8];
        float4 bh = *(const float4*)&bias[c * 8 + 4];
        __half2 h0 = __floats2half2_rn(fmaxf(fmaf(a[0], dd, bl.x), 0.f),
                                       fmaxf(fmaf(a[1], dd, bl.y), 0.f));
        __half2 h1v = __floats2half2_rn(fmaxf(fmaf(a[2], dd, bl.z), 0.f),
                                        fmaxf(fmaf(a[3], dd, bl.w), 0.f));
        __half2 h2v = __floats2half2_rn(fmaxf(fmaf(a[4], dd, bh.x), 0.f),
                                        fmaxf(fmaf(a[5], dd, bh.y), 0.f));
        __half2 h3 = __floats2half2_rn(fmaxf(fmaf(a[6], dd, bh.z), 0.f),
                                       fmaxf(fmaf(a[7], dd, bh.w), 0.f));
        uint4 pk = make_uint4(*(unsigned*)&h0, *(unsigned*)&h1v,
                              *(unsigned*)&h2v, *(unsigned*)&h3);
        ((uint4*)(x2 + (size_t)dc * HID))[c] = pk;
    }
}

// ---------------- mean-pool + head: one wave per graph, contiguous fp16 rows --------
__global__ void k_poolhead(const __half* __restrict__ x2, const int* __restrict__ gstart,
                           const float* __restrict__ Wout, const float* __restrict__ bout,
                           float* __restrict__ out) {
    int g = (blockIdx.x * blockDim.x + threadIdx.x) >> 6;  // graph id
    if (g >= NG) return;
    int lane = threadIdx.x & 63;
    int beg = gstart[g], end = gstart[g + 1];
    const __half2* rows = (const __half2*)x2;
    float sx = 0.f, sy = 0.f;
    for (int n = beg; n < end; ++n) {
        float2 v = __half22float2(rows[(size_t)n * 64 + lane]);
        sx += v.x; sy += v.y;
    }
    float inv = (end > beg) ? 1.f / (float)(end - beg) : 1.f;
    sx *= inv; sy *= inv;
    float wo0[NCLS], wo1[NCLS];
    {
        const float4* p0 = (const float4*)&Wout[(size_t)(2 * lane) * NCLS];
        const float4* p1 = (const float4*)&Wout[(size_t)(2 * lane + 1) * NCLS];
#pragma unroll
        for (int j = 0; j < 4; ++j) {
            float4 a = p0[j]; wo0[4*j] = a.x; wo0[4*j+1] = a.y; wo0[4*j+2] = a.z; wo0[4*j+3] = a.w;
            float4 c = p1[j]; wo1[4*j] = c.x; wo1[4*j+1] = c.y; wo1[4*j+2] = c.z; wo1[4*j+3] = c.w;
        }
    }
#pragma unroll
    for (int c = 0; c < NCLS; ++c) {
        float p = fmaf(sx, wo0[c], sy * wo1[c]);
#pragma unroll
        for (int s = 1; s < 64; s <<= 1) p += __shfl_xor(p, s, 64);
        if (lane == c) out[(size_t)g * NCLS + c] = p + bout[c];
    }
}

static inline size_t align_up(size_t v, size_t a) { return (v + a - 1) & ~(a - 1); }

extern "C" void kernel_launch(void* const* d_in, const int* in_sizes, int n_in,
                              void* d_out, int out_size, void* d_ws, size_t ws_size,
                              hipStream_t stream) {
    const int*   node_ids = (const int*)d_in[0];
    const int*   edge     = (const int*)d_in[1];
    const int*   batch    = (const int*)d_in[2];
    const float* embed    = (const float*)d_in[3];
    const float* W1       = (const float*)d_in[4];
    const float* b1       = (const float*)d_in[5];
    const float* W2       = (const float*)d_in[6];
    const float* b2       = (const float*)d_in[7];
    const float* Wout     = (const float*)d_in[8];
    const float* bout     = (const float*)d_in[9];
    float* out = (float*)d_out;

    const int N = in_sizes[0];
    const int E = in_sizes[1] / 2;
    const int V = in_sizes[3] / EMB;

    // 256B-aligned workspace layout (~106 MB)
    char* wsb = (char*)d_ws;
    size_t off = 0;
    float*    dinv   = (float*)(wsb + off);    off = align_up(off + (size_t)N * 4, 256);
    int*      deg4   = (int*)(wsb + off);      off = align_up(off + (size_t)N * 16, 256);
    int*      gstart = (int*)(wsb + off);      off = align_up(off + (size_t)(NG + 1) * 4, 256);
    __half*   wt2    = (__half*)(wsb + off);   off = align_up(off + (size_t)HID * HID * 2, 256);
    __half*   xw     = (__half*)(wsb + off);   off = align_up(off + (size_t)V * HID * 2, 256);
    unsigned* bucket = (unsigned*)(wsb + off); off = align_up(off + ((size_t)N << CAPLOG) * 4, 256);
    __half*   h1     = (__half*)(wsb + off);   off = align_up(off + (size_t)N * HID * 2, 256);
    __half*   h2     = (__half*)(wsb + off);   off = align_up(off + (size_t)N * HID * 2, 256);
    __half*   x2     = (__half*)(wsb + off);   off = align_up(off + (size_t)N * HID * 2, 256);

    const int* src = edge;
    const int* dst = edge + E;

    // ---- build: zero counters -> fused deg+bucket fill -> prep (xw/wt2/bounds/dinv) ----
    k_zero<<<(N + 255) / 256, 256, 0, stream>>>((uint4*)deg4, N);   // N uint4 = N*16 B
    k_degfill<<<(E + 255) / 256, 256, 0, stream>>>(src, dst, node_ids, E, deg4, bucket);
    {
        int xwB  = (V * 64 + 255) / 256;
        int bndB = (N + 1 + 255) / 256;
        int dvB  = (N + 255) / 256;
        k_prep<<<xwB + 64 + bndB + dvB, 256, 0, stream>>>(embed, W1, W2, batch, deg4,
                                                          xw, wt2, gstart, dinv, V, N, xwB, bndB);
    }

    const int NW = (N + 3) / 4;   // 4 nodes per wave

    // ---- layer 1: 4-node-per-wave gather in XW space (bias+relu fused) -> h1 fp16 ----
    k_gather1<<<(NW * 64 + 255) / 256, 256, 0, stream>>>(node_ids, xw, bucket, deg4,
                                                         dinv, b1, h1, N);

    // ---- layer 2: MFMA matmul (swapped operands) -> fp16, then 4-node gather ----
    k_mm2_mfma<<<(N + MMB - 1) / MMB, 256, 0, stream>>>(h1, wt2, dinv, h2, N);
    k_gather2<<<(NW * 64 + 255) / 256, 256, 0, stream>>>(h2, bucket, deg4, dinv, b2, x2, N);

    // ---- mean-pool + head ----
    k_poolhead<<<(NG * 64 + 255) / 256, 256, 0, stream>>>(x2, gstart, Wout, bout, out);
}

// Round 23
// 190.842 us; speedup vs baseline: 1.0962x; 1.0962x over previous
//
#include <hip/hip_runtime.h>
#include <hip/hip_fp16.h>

#define HID 128
#define EMB 64
#define NG  8192
#define NCLS 16
#define SRCBITS 17    // N=100000 < 2^17; VOCAB=5000 < 2^13
#define SMASK ((1u << SRCBITS) - 1)
#define MMB 64        // nodes per matmul block
#define CAPLOG 6      // 64 slots per node bucket (deg ~ Poisson(10), max ~30)
#define CAP (1 << CAPLOG)

typedef _Float16 f16x8 __attribute__((ext_vector_type(8)));
typedef float    f32x4 __attribute__((ext_vector_type(4)));

// fpext(f16) feeding fmaf -> v_fma_mix_f32
__device__ __forceinline__ void fma8(float* a, uint4 r, float w) {
    const _Float16* h = (const _Float16*)&r;
#pragma unroll
    for (int k = 0; k < 8; ++k) a[k] = fmaf((float)h[k], w, a[k]);
}

// ---------------- zero the padded counter array ----------------
__global__ void k_zero(uint4* __restrict__ p, int n4) {
    int i = blockIdx.x * 256 + threadIdx.x;
    if (i < n4) p[i] = make_uint4(0u, 0u, 0u, 0u);
}

// ---------------- fused degree + bucket fill: 4 edges/thread (intra-thread MLP) -----
// deg4[4*n] = count for node n (16B stride); bucket[n*CAP + pos] = (vid<<17)|src.
__global__ void k_degfill(const int* __restrict__ src, const int* __restrict__ dst,
                          const int* __restrict__ ids, int E,
                          int* __restrict__ deg4, unsigned* __restrict__ bucket) {
    int e4 = (blockIdx.x * 256 + threadIdx.x) * 4;
    if (e4 + 4 <= E) {
        int4 s4 = *(const int4*)&src[e4];
        int4 d4 = *(const int4*)&dst[e4];
        int p0 = atomicAdd(&deg4[(size_t)d4.x * 4], 1);
        int p1 = atomicAdd(&deg4[(size_t)d4.y * 4], 1);
        int p2 = atomicAdd(&deg4[(size_t)d4.z * 4], 1);
        int p3 = atomicAdd(&deg4[(size_t)d4.w * 4], 1);
        if (p0 < CAP) bucket[((size_t)d4.x << CAPLOG) + p0] = ((unsigned)ids[s4.x] << SRCBITS) | (unsigned)s4.x;
        if (p1 < CAP) bucket[((size_t)d4.y << CAPLOG) + p1] = ((unsigned)ids[s4.y] << SRCBITS) | (unsigned)s4.y;
        if (p2 < CAP) bucket[((size_t)d4.z << CAPLOG) + p2] = ((unsigned)ids[s4.z] << SRCBITS) | (unsigned)s4.z;
        if (p3 < CAP) bucket[((size_t)d4.w << CAPLOG) + p3] = ((unsigned)ids[s4.w] << SRCBITS) | (unsigned)s4.w;
    } else {
        for (int e = e4; e < E; ++e) {
            int s = src[e], d = dst[e];
            int pos = atomicAdd(&deg4[(size_t)d * 4], 1);
            if (pos < CAP) bucket[((size_t)d << CAPLOG) + pos] = ((unsigned)ids[s] << SRCBITS) | (unsigned)s;
        }
    }
}

// ---------------- fused prep: XW=embed@W1 fp16 | wt2=W2^T fp16 | bounds | dinv ------
__global__ void k_prep(const float* __restrict__ embed, const float* __restrict__ W1,
                       const float* __restrict__ W2, const int* __restrict__ batch,
                       const int* __restrict__ deg4,
                       __half* __restrict__ xw, __half* __restrict__ wt2,
                       int* __restrict__ gstart, float* __restrict__ dinv,
                       int V, int N, int xwB, int bndB) {
    int b = (int)blockIdx.x;
    if (b < xwB) {
        int v = (b * 256 + threadIdx.x) >> 6;
        if (v >= V) return;
        int lane = threadIdx.x & 63;
        float ev = embed[(size_t)v * EMB + lane];
        float a0 = 0.f, a1 = 0.f;
#pragma unroll
        for (int k = 0; k < EMB; ++k) {
            float e = __shfl(ev, k, 64);
            float2 w = *(const float2*)&W1[k * HID + 2 * lane];
            a0 = fmaf(e, w.x, a0);
            a1 = fmaf(e, w.y, a1);
        }
        ((__half2*)xw)[(size_t)v * 64 + lane] = __floats2half2_rn(a0, a1);
    } else if (b < xwB + 64) {
        int i = (b - xwB) * 256 + threadIdx.x;   // 64 blocks: 16384
        int c = i >> 7, k = i & 127;
        wt2[i] = __float2half(W2[k * HID + c]);
    } else if (b < xwB + 64 + bndB) {
        int n = (b - xwB - 64) * 256 + threadIdx.x;
        if (n > N) return;
        int bc = (n < N) ? batch[n] : NG;
        int bp = (n > 0) ? batch[n - 1] : -1;
        for (int g = bp + 1; g <= bc; ++g) gstart[g] = n;
    } else {
        int n = (b - xwB - 64 - bndB) * 256 + threadIdx.x;
        if (n < N) dinv[n] = rsqrtf((float)(deg4[(size_t)n * 4] + 1));  // +1 self-loop
    }
}

// ---------------- layer-1 gather: FOUR nodes per wave (16 lanes each) ----------------
// h1[d] = relu( dd*( dd*XW[ids[d]] + sum_e dinv[s_e]*XW[vid_e] ) + b1 )
__global__ void k_gather1(const int* __restrict__ ids, const __half* __restrict__ xw,
                          const unsigned* __restrict__ bucket, const int* __restrict__ deg4,
                          const float* __restrict__ dinv, const float* __restrict__ bias,
                          __half* __restrict__ h1, int N) {
    int wid = (blockIdx.x * blockDim.x + threadIdx.x) >> 6;
    int lane = threadIdx.x & 63;
    int q = lane >> 4;                        // node sub-index 0..3
    int d = wid * 4 + q;
    bool act = d < N;
    int dc = act ? d : N - 1;
    unsigned cb = (unsigned)(lane & 15) << 4; // 16B-chunk byte offset in a 256B row
    int dg = min(deg4[(size_t)dc * 4], CAP);
    int beg = dc << CAPLOG, end = beg + dg;
    float dd = dinv[dc];
    const char* xwb = (const char*)xw;
    float a[8] = {0.f, 0.f, 0.f, 0.f, 0.f, 0.f, 0.f, 0.f};
    {                                          // self term
        uint4 r = *(const uint4*)(xwb + (((unsigned)ids[dc] << 8) | cb));
        fma8(a, r, dd);
    }
    for (int i = beg; i < end; i += 4) {       // 4 edges/node/iter
        float w[4]; unsigned ro[4]; uint4 r[4];
#pragma unroll
        for (int j = 0; j < 4; ++j) {
            int idx = i + j;
            bool v = idx < end;
            unsigned p = bucket[v ? idx : beg];
            w[j] = v ? dinv[p & SMASK] : 0.f;
            ro[j] = v ? (((p >> SRCBITS) << 8) | cb) : cb;
        }
#pragma unroll
        for (int j = 0; j < 4; ++j) r[j] = *(const uint4*)(xwb + ro[j]);
#pragma unroll
        for (int j = 0; j < 4; ++j) fma8(a, r[j], w[j]);
    }
    if (act) {
        int c = lane & 15;
        float4 bl = *(const float4*)&bias[c * 8];
        float4 bh = *(const float4*)&bias[c * 8 + 4];
        __half2 h0 = __floats2half2_rn(fmaxf(fmaf(a[0], dd, bl.x), 0.f),
                                       fmaxf(fmaf(a[1], dd, bl.y), 0.f));
        __half2 h1v = __floats2half2_rn(fmaxf(fmaf(a[2], dd, bl.z), 0.f),
                                        fmaxf(fmaf(a[3], dd, bl.w), 0.f));
        __half2 h2v = __floats2half2_rn(fmaxf(fmaf(a[4], dd, bh.x), 0.f),
                                        fmaxf(fmaf(a[5], dd, bh.y), 0.f));
        __half2 h3 = __floats2half2_rn(fmaxf(fmaf(a[6], dd, bh.z), 0.f),
                                       fmaxf(fmaf(a[7], dd, bh.w), 0.f));
        uint4 pk = make_uint4(*(unsigned*)&h0, *(unsigned*)&h1v,
                              *(unsigned*)&h2v, *(unsigned*)&h3);
        ((uint4*)(h1 + (size_t)dc * HID))[c] = pk;
    }
}

// ---------------- layer-2 matmul via MFMA (swapped operands): h2 = (h1@W2)*dinv -----
__global__ __launch_bounds__(256) void k_mm2_mfma(const __half* __restrict__ h1,
                                                  const __half* __restrict__ wt,
                                                  const float* __restrict__ dinv,
                                                  __half* __restrict__ h2, int N) {
    int tid = threadIdx.x;
    int w = tid >> 6, l = tid & 63;
    int base = blockIdx.x * MMB + w * 16;
    int lrow = l & 15, lkg = l >> 4;
    int node = base + lrow;
    int nc = node < N ? node : N - 1;
    const f16x8* ap = (const f16x8*)(h1 + (size_t)nc * HID);
    f16x8 a0 = ap[0 * 4 + lkg], a1 = ap[1 * 4 + lkg];
    f16x8 a2 = ap[2 * 4 + lkg], a3 = ap[3 * 4 + lkg];
    f32x4 acc[8];
#pragma unroll
    for (int ct = 0; ct < 8; ++ct) acc[ct] = (f32x4){0.f, 0.f, 0.f, 0.f};
    const f16x8* wp = (const f16x8*)wt;   // wt[c][k]: row c = 16 f16x8 chunks
#pragma unroll
    for (int ct = 0; ct < 8; ++ct) {
        const f16x8* bp = wp + (ct * 16 + lrow) * 16 + lkg;
        f16x8 b0 = bp[0], b1 = bp[4], b2 = bp[8], b3 = bp[12];
        acc[ct] = __builtin_amdgcn_mfma_f32_16x16x32_f16(b0, a0, acc[ct], 0, 0, 0);
        acc[ct] = __builtin_amdgcn_mfma_f32_16x16x32_f16(b1, a1, acc[ct], 0, 0, 0);
        acc[ct] = __builtin_amdgcn_mfma_f32_16x16x32_f16(b2, a2, acc[ct], 0, 0, 0);
        acc[ct] = __builtin_amdgcn_mfma_f32_16x16x32_f16(b3, a3, acc[ct], 0, 0, 0);
    }
    if (node < N) {
        float sc = dinv[node];
#pragma unroll
        for (int ct = 0; ct < 8; ++ct) {
            int wc = ct * 16 + lkg * 4;       // 4 consecutive weight-cols
            __half2 lo = __floats2half2_rn(acc[ct][0] * sc, acc[ct][1] * sc);
            __half2 hi = __floats2half2_rn(acc[ct][2] * sc, acc[ct][3] * sc);
            uint2 pk = make_uint2(*(unsigned*)&lo, *(unsigned*)&hi);
            *(uint2*)&h2[(size_t)node * HID + wc] = pk;
        }
    }
}

// ---------------- layer-2 gather: FOUR nodes per wave ----------------
// x2[d] = relu( dd*(h2[d] + sum h2[s]) + b2 )
__global__ void k_gather2(const __half* __restrict__ h2, const unsigned* __restrict__ bucket,
                          const int* __restrict__ deg4, const float* __restrict__ dinv,
                          const float* __restrict__ bias, __half* __restrict__ x2, int N) {
    int wid = (blockIdx.x * blockDim.x + threadIdx.x) >> 6;
    int lane = threadIdx.x & 63;
    int q = lane >> 4;
    int d = wid * 4 + q;
    bool act = d < N;
    int dc = act ? d : N - 1;
    unsigned cb = (unsigned)(lane & 15) << 4;
    int dg = min(deg4[(size_t)dc * 4], CAP);
    int beg = dc << CAPLOG, end = beg + dg;
    float dd = dinv[dc];
    const char* hb = (const char*)h2;
    float a[8] = {0.f, 0.f, 0.f, 0.f, 0.f, 0.f, 0.f, 0.f};
    {                                          // self term (prescaled by dinv already)
        uint4 r = *(const uint4*)(hb + (((unsigned)dc << 8) | cb));
        fma8(a, r, 1.f);
    }
    for (int i = beg; i < end; i += 4) {
        float w[4]; unsigned ro[4]; uint4 r[4];
#pragma unroll
        for (int j = 0; j < 4; ++j) {
            int idx = i + j;
            bool v = idx < end;
            unsigned p = bucket[v ? idx : beg];
            w[j] = v ? 1.f : 0.f;
            ro[j] = v ? (((p & SMASK) << 8) | cb) : cb;
        }
#pragma unroll
        for (int j = 0; j < 4; ++j) r[j] = *(const uint4*)(hb + ro[j]);
#pragma unroll
        for (int j = 0; j < 4; ++j) fma8(a, r[j], w[j]);
    }
    if (act) {
        int c = lane & 15;
        float4 bl = *(const float4*)&bias[c * 8];
        float4 bh = *(const float4*)&bias[c * 8 + 4];
        __half2 h0 = __floats2half2_rn(fmaxf(fmaf(a[0], dd, bl.x), 0.f),
                                       fmaxf(fmaf(a[1], dd, bl.y), 0.f));
        __half2 h1v = __floats2half2_rn(fmaxf(fmaf(a[2], dd, bl.z), 0.f),
                                        fmaxf(fmaf(a[3], dd, bl.w), 0.f));
        __half2 h2v = __floats2half2_rn(fmaxf(fmaf(a[4], dd, bh.x), 0.f),
                                        fmaxf(fmaf(a[5], dd, bh.y), 0.f));
        __half2 h3 = __floats2half2_rn(fmaxf(fmaf(a[6], dd, bh.z), 0.f),
                                       fmaxf(fmaf(a[7], dd, bh.w), 0.f));
        uint4 pk = make_uint4(*(unsigned*)&h0, *(unsigned*)&h1v,
                              *(unsigned*)&h2v, *(unsigned*)&h3);
        ((uint4*)(x2 + (size_t)dc * HID))[c] = pk;
    }
}

// ---------------- mean-pool + head: one wave per graph, contiguous fp16 rows --------
__global__ void k_poolhead(const __half* __restrict__ x2, const int* __restrict__ gstart,
                           const float* __restrict__ Wout, const float* __restrict__ bout,
                           float* __restrict__ out) {
    int g = (blockIdx.x * blockDim.x + threadIdx.x) >> 6;  // graph id
    if (g >= NG) return;
    int lane = threadIdx.x & 63;
    int beg = gstart[g], end = gstart[g + 1];
    const __half2* rows = (const __half2*)x2;
    float sx = 0.f, sy = 0.f;
    for (int n = beg; n < end; ++n) {
        float2 v = __half22float2(rows[(size_t)n * 64 + lane]);
        sx += v.x; sy += v.y;
    }
    float inv = (end > beg) ? 1.f / (float)(end - beg) : 1.f;
    sx *= inv; sy *= inv;
    float wo0[NCLS], wo1[NCLS];
    {
        const float4* p0 = (const float4*)&Wout[(size_t)(2 * lane) * NCLS];
        const float4* p1 = (const float4*)&Wout[(size_t)(2 * lane + 1) * NCLS];
#pragma unroll
        for (int j = 0; j < 4; ++j) {
            float4 a = p0[j]; wo0[4*j] = a.x; wo0[4*j+1] = a.y; wo0[4*j+2] = a.z; wo0[4*j+3] = a.w;
            float4 c = p1[j]; wo1[4*j] = c.x; wo1[4*j+1] = c.y; wo1[4*j+2] = c.z; wo1[4*j+3] = c.w;
        }
    }
#pragma unroll
    for (int c = 0; c < NCLS; ++c) {
        float p = fmaf(sx, wo0[c], sy * wo1[c]);
#pragma unroll
        for (int s = 1; s < 64; s <<= 1) p += __shfl_xor(p, s, 64);
        if (lane == c) out[(size_t)g * NCLS + c] = p + bout[c];
    }
}

static inline size_t align_up(size_t v, size_t a) { return (v + a - 1) & ~(a - 1); }

extern "C" void kernel_launch(void* const* d_in, const int* in_sizes, int n_in,
                              void* d_out, int out_size, void* d_ws, size_t ws_size,
                              hipStream_t stream) {
    const int*   node_ids = (const int*)d_in[0];
    const int*   edge     = (const int*)d_in[1];
    const int*   batch    = (const int*)d_in[2];
    const float* embed    = (const float*)d_in[3];
    const float* W1       = (const float*)d_in[4];
    const float* b1       = (const float*)d_in[5];
    const float* W2       = (const float*)d_in[6];
    const float* b2       = (const float*)d_in[7];
    const float* Wout     = (const float*)d_in[8];
    const float* bout     = (const float*)d_in[9];
    float* out = (float*)d_out;

    const int N = in_sizes[0];
    const int E = in_sizes[1] / 2;
    const int V = in_sizes[3] / EMB;

    // 256B-aligned workspace layout (~106 MB)
    char* wsb = (char*)d_ws;
    size_t off = 0;
    float*    dinv   = (float*)(wsb + off);    off = align_up(off + (size_t)N * 4, 256);
    int*      deg4   = (int*)(wsb + off);      off = align_up(off + (size_t)N * 16, 256);
    int*      gstart = (int*)(wsb + off);      off = align_up(off + (size_t)(NG + 1) * 4, 256);
    __half*   wt2    = (__half*)(wsb + off);   off = align_up(off + (size_t)HID * HID * 2, 256);
    __half*   xw     = (__half*)(wsb + off);   off = align_up(off + (size_t)V * HID * 2, 256);
    unsigned* bucket = (unsigned*)(wsb + off); off = align_up(off + ((size_t)N << CAPLOG) * 4, 256);
    __half*   h1     = (__half*)(wsb + off);   off = align_up(off + (size_t)N * HID * 2, 256);
    __half*   h2     = (__half*)(wsb + off);   off = align_up(off + (size_t)N * HID * 2, 256);
    __half*   x2     = (__half*)(wsb + off);   off = align_up(off + (size_t)N * HID * 2, 256);

    const int* src = edge;
    const int* dst = edge + E;

    // ---- build: zero counters -> fused deg+bucket fill -> prep (xw/wt2/bounds/dinv) ----
    k_zero<<<(N + 255) / 256, 256, 0, stream>>>((uint4*)deg4, N);   // N uint4 = N*16 B
    k_degfill<<<(E / 4 + 255) / 256, 256, 0, stream>>>(src, dst, node_ids, E, deg4, bucket);
    {
        int xwB  = (V * 64 + 255) / 256;
        int bndB = (N + 1 + 255) / 256;
        int dvB  = (N + 255) / 256;
        k_prep<<<xwB + 64 + bndB + dvB, 256, 0, stream>>>(embed, W1, W2, batch, deg4,
                                                          xw, wt2, gstart, dinv, V, N, xwB, bndB);
    }

    const int NW = (N + 3) / 4;   // 4 nodes per wave

    // ---- layer 1: 4-node-per-wave gather in XW space (bias+relu fused) -> h1 fp16 ----
    k_gather1<<<(NW * 64 + 255) / 256, 256, 0, stream>>>(node_ids, xw, bucket, deg4,
                                                         dinv, b1, h1, N);

    // ---- layer 2: MFMA matmul (swapped operands) -> fp16, then 4-node gather ----
    k_mm2_mfma<<<(N + MMB - 1) / MMB, 256, 0, stream>>>(h1, wt2, dinv, h2, N);
    k_gather2<<<(NW * 64 + 255) / 256, 256, 0, stream>>>(h2, bucket, deg4, dinv, b2, x2, N);

    // ---- mean-pool + head ----
    k_poolhead<<<(NG * 64 + 255) / 256, 256, 0, stream>>>(x2, gstart, Wout, bout, out);
}